// Round 4
// baseline (801.886 us; speedup 1.0000x reference)
//
#include <hip/hip_runtime.h>

typedef __attribute__((ext_vector_type(8))) __bf16 bf16x8;
typedef __attribute__((ext_vector_type(4))) __bf16 bf16x4;
typedef __attribute__((ext_vector_type(4))) float f32x4;

#define TOKENS 16384   // B*T
#define DDIM   2048
#define LAT    256
#define FFND   1024

// ---------------------------------------------------------------------------
// async global->LDS 16B copy (dest = wave-uniform base + lane*16B)
// ---------------------------------------------------------------------------
__device__ __forceinline__ void gload_lds16(const __bf16* g, __bf16* l) {
  __builtin_amdgcn_global_load_lds(
      (const __attribute__((address_space(1))) void*)g,
      (__attribute__((address_space(3))) void*)l, 16, 0, 0);
}

// ---------------------------------------------------------------------------
// Batched transpose + fp32->bf16 convert: src (batch, R, C) f32 -> dst (batch, C, R) bf16
// ---------------------------------------------------------------------------
__global__ void transpose_f32_bf16(const float* __restrict__ src, __bf16* __restrict__ dst,
                                   int R, int C) {
  __shared__ float tile[32][33];  // +1 pad breaks bank conflicts
  const int b = blockIdx.z;
  src += (size_t)b * R * C;
  dst += (size_t)b * R * C;
  const int c0 = blockIdx.x * 32, r0 = blockIdx.y * 32;
  const int tx = threadIdx.x & 31, ty = threadIdx.x >> 5;  // 256 threads: ty 0..7
  for (int i = ty; i < 32; i += 8)
    tile[i][tx] = src[(size_t)(r0 + i) * C + c0 + tx];
  __syncthreads();
  for (int i = ty; i < 32; i += 8)
    dst[(size_t)(c0 + i) * R + r0 + tx] = (__bf16)tile[tx][i];
}

// ---------------------------------------------------------------------------
// K0a: partial eo = silu(emb) @ emb_W over a 256-wide k-chunk.
// ---------------------------------------------------------------------------
__global__ void k0_partial(const float* __restrict__ emb, const float* __restrict__ embW,
                           float* __restrict__ pp) {
  __shared__ float se[4 * 256];
  const int tid = threadIdx.x;
  const int kc = blockIdx.y;
  const int kb = kc * 256;
  for (int i = tid; i < 1024; i += 256) {
    const int bb = i >> 8, kk = i & 255;
    float v = emb[bb * 2048 + kb + kk];
    se[i] = v / (1.f + __expf(-v));
  }
  __syncthreads();
  const int j = blockIdx.x * 256 + tid;
  float a0 = 0.f, a1 = 0.f, a2 = 0.f, a3 = 0.f;
  for (int k = 0; k < 256; ++k) {
    float wv = embW[(size_t)(kb + k) * 4096 + j];
    a0 += se[k] * wv;
    a1 += se[256 + k] * wv;
    a2 += se[512 + k] * wv;
    a3 += se[768 + k] * wv;
  }
  pp[(size_t)(kc * 4 + 0) * 4096 + j] = a0;
  pp[(size_t)(kc * 4 + 1) * 4096 + j] = a1;
  pp[(size_t)(kc * 4 + 2) * 4096 + j] = a2;
  pp[(size_t)(kc * 4 + 3) * 4096 + j] = a3;
}

// K0b: reduce partials + bias -> ss[b*4096 + j] (fp32)
__global__ void k0_reduce(const float* __restrict__ pp, const float* __restrict__ embb,
                          float* __restrict__ ss) {
  const int j = blockIdx.x * 256 + threadIdx.x;
  const float bb = embb[j];
#pragma unroll
  for (int b = 0; b < 4; ++b) {
    float s = bb;
#pragma unroll
    for (int kc = 0; kc < 8; ++kc) s += pp[(size_t)(kc * 4 + b) * 4096 + j];
    ss[b * 4096 + j] = s;
  }
}

// ---------------------------------------------------------------------------
// Weight prefetch: all 16 fragments of a wave's 32-row x 256-K slab -> VGPRs.
// ---------------------------------------------------------------------------
__device__ __forceinline__ void wload(const __bf16* __restrict__ wsrc, int wstride,
                                      int ln, int q, bf16x8 (&bw)[16]) {
#pragma unroll
  for (int k0 = 0; k0 < 8; ++k0)
#pragma unroll
    for (int j = 0; j < 2; ++j)
      bw[k0 * 2 + j] = *(const bf16x8*)(wsrc + (size_t)(j * 16 + ln) * wstride + k0 * 32 + q * 8);
}

// K=256 MFMA sweep on prefetched weight frags (identical MFMA order to v4).
__device__ __forceinline__ void gemm_pre(const bf16x8 (&bw)[16], const __bf16* lds,
                                         int swz, int ln, int q, f32x4 (&acc)[2][4]) {
#pragma unroll
  for (int k0 = 0; k0 < 8; ++k0) {
    bf16x8 af[4];
#pragma unroll
    for (int i = 0; i < 4; ++i)
      af[i] = *(const bf16x8*)(lds + (i * 16 + ln) * 256 + ((k0 * 32 + q * 8) ^ swz));
#pragma unroll
    for (int j = 0; j < 2; ++j)
#pragma unroll
      for (int i = 0; i < 4; ++i)
        acc[j][i] = __builtin_amdgcn_mfma_f32_16x16x32_bf16(bw[k0 * 2 + j], af[i], acc[j][i], 0, 0, 0);
  }
}

// ---------------------------------------------------------------------------
// K1: fused expert FFN. Block = 64 tokens x 1 expert, 8 waves (512 thr).
//
// v5: ILP attack. v4's VGPR_Count=60 (launch_bounds(512,4) cap 128, accs in
//     AGPR) left room for ~2 weight loads in flight vs ~300cyc L2 latency ->
//     all pipes <30% busy, waves waiting. Now: launch_bounds(512,2) (cap 256,
//     8 waves/CU) + full-K weight prefetch (bw[16] = 64 VGPR). W2(fc) frags
//     are issued BEFORE the hs-ready barrier -- the compiler's vmcnt(0) drain
//     at s_barrier makes them resident right after it, paying latency once
//     per segment under the barrier wait. GEMM1(fc+1)'s loads then issue
//     underneath GEMM2's 64-MFMA sweep. Bit-exact vs v4.
// ---------------------------------------------------------------------------
__launch_bounds__(512, 2)
__global__ void k1_expert_ffn(const float* __restrict__ x, const __bf16* __restrict__ W1T,
                              const float* __restrict__ b1, const __bf16* __restrict__ W2T,
                              const float* __restrict__ b2, __bf16* __restrict__ y) {
  __shared__ __bf16 xs[64 * 256];     // 32 KB  x tile [m][l] (bf16, swizzled)
  __shared__ __bf16 hs[64 * 256];     // 32 KB  gelu(h) chunk [m][f_local] (swizzled)

  const int tid = threadIdx.x;
  const int w = tid >> 6;             // 0..7
  const int lane = tid & 63;
  const int q = lane >> 4;
  const int ln = lane & 15;
  const int m0 = blockIdx.x * 64;
  const int e = blockIdx.y;
  const int swz = (ln & 7) << 3;

  // stage x tile (64 x 256 fp32) -> bf16 LDS (swizzled); 8 rows/pass, 8 passes
  {
    const int r0 = tid >> 6;
    const int c = (tid & 63) * 4;
#pragma unroll
    for (int p = 0; p < 8; ++p) {
      const int r = r0 + p * 8;
      f32x4 v = *(const f32x4*)(x + (size_t)(m0 + r) * DDIM + e * LAT + c);
      bf16x4 o;
      o[0] = (__bf16)v[0]; o[1] = (__bf16)v[1]; o[2] = (__bf16)v[2]; o[3] = (__bf16)v[3];
      *(bf16x4*)(xs + r * 256 + (c ^ ((r & 7) << 3))) = o;
    }
  }

  // acc_y[j][i]: D row = latent l = w*32 + j*16 + q*4 + r, col = token = i*16 + ln
  f32x4 acc_y[2][4];
#pragma unroll
  for (int j = 0; j < 2; ++j) {
    f32x4 bv = *(const f32x4*)(b2 + e * LAT + w * 32 + j * 16 + q * 4);
#pragma unroll
    for (int i = 0; i < 4; ++i) acc_y[j][i] = bv;
  }

  f32x4 acc_h[2][4];
  bf16x8 bw[16];

  // issue W1(fc=0) prefetch before the xs barrier (drained by it -> resident)
  wload(W1T + ((size_t)e * FFND + w * 32) * LAT, LAT, ln, q, bw);

  __syncthreads();  // xs ready (+ W1 fc0 frags resident)

  // GEMM1 chunk 0 -> acc_h
#pragma unroll
  for (int j = 0; j < 2; ++j) {
    f32x4 bv = *(const f32x4*)(b1 + e * FFND + w * 32 + j * 16 + q * 4);
#pragma unroll
    for (int i = 0; i < 4; ++i) acc_h[j][i] = bv;
  }
  gemm_pre(bw, xs, swz, ln, q, acc_h);

  for (int fc = 0; fc < 4; ++fc) {
    // pack GELU(acc_h) -> hs (hs fully consumed before the barrier below)
#pragma unroll
    for (int j = 0; j < 2; ++j)
#pragma unroll
      for (int i = 0; i < 4; ++i) {
        const int tok = i * 16 + ln;
        const int fcol = w * 32 + j * 16 + q * 4;
        bf16x4 o;
#pragma unroll
        for (int r = 0; r < 4; ++r) {
          float vv = acc_h[j][i][r];
          // gelu(v) = v * sigmoid(1.5957691*v*(1+0.044715*v^2))  [tanh form]
          float u2 = -1.5957691216057308f * vv * (1.0f + 0.044715f * vv * vv);
          u2 = fminf(u2, 80.f);  // overflow guard
          float ge = vv * __builtin_amdgcn_rcpf(1.0f + __expf(u2));
          o[r] = (__bf16)ge;
        }
        *(bf16x4*)(hs + tok * 256 + (fcol ^ ((tok & 7) << 3))) = o;
      }

    // prefetch W2(fc) frags; barrier's vmcnt drain makes them resident after it
    wload(W2T + ((size_t)(e * LAT + w * 32)) * FFND + fc * 256, FFND, ln, q, bw);

    __syncthreads();  // hs ready

    // GEMM2(fc) on resident frags
    gemm_pre(bw, hs, swz, ln, q, acc_y);

    if (fc < 3) {
      // GEMM1(fc+1): loads issue underneath GEMM2's MFMA sweep above
      wload(W1T + ((size_t)e * FFND + (fc + 1) * 256 + w * 32) * LAT, LAT, ln, q, bw);
#pragma unroll
      for (int j = 0; j < 2; ++j) {
        f32x4 bv = *(const f32x4*)(b1 + e * FFND + (fc + 1) * 256 + w * 32 + j * 16 + q * 4);
#pragma unroll
        for (int i = 0; i < 4; ++i) acc_h[j][i] = bv;
      }
      gemm_pre(bw, xs, swz, ln, q, acc_h);
    }

    __syncthreads();  // hs consumed by all waves before next pack overwrites it
  }

  // store y (bf16): lane holds 4 consecutive latent cols at one token -> b64 stores
#pragma unroll
  for (int j = 0; j < 2; ++j)
#pragma unroll
    for (int i = 0; i < 4; ++i) {
      const int tok = i * 16 + ln;
      const int l = w * 32 + j * 16 + q * 4;
      bf16x4 o;
#pragma unroll
      for (int r = 0; r < 4; ++r) o[r] = (__bf16)acc_y[j][i][r];
      *(bf16x4*)(y + (size_t)(m0 + tok) * DDIM + e * LAT + l) = o;
    }
}

// ---------------------------------------------------------------------------
// K2: per-token LN + (1+scale)/shift modulation + SiLU, in place on y (bf16).
// ---------------------------------------------------------------------------
__global__ void k2_ln_mod_silu(const float* __restrict__ ss, const float* __restrict__ g,
                               const float* __restrict__ bb, __bf16* __restrict__ y) {
  __shared__ float red[8];
  const int t = blockIdx.x;     // token
  const int b = t >> 12;        // batch = token / 4096
  const int tid = threadIdx.x;
  __bf16* row = y + (size_t)t * DDIM;
  bf16x8 v8 = *(bf16x8*)(row + tid * 8);
  float v[8], s = 0.f, sq = 0.f;
#pragma unroll
  for (int i = 0; i < 8; ++i) {
    v[i] = (float)v8[i];
    s += v[i];
    sq += v[i] * v[i];
  }
#pragma unroll
  for (int off = 32; off > 0; off >>= 1) {
    s += __shfl_down(s, off);
    sq += __shfl_down(sq, off);
  }
  if ((tid & 63) == 0) {
    red[tid >> 6] = s;
    red[4 + (tid >> 6)] = sq;
  }
  __syncthreads();
  const float S = red[0] + red[1] + red[2] + red[3];
  const float SQ = red[4] + red[5] + red[6] + red[7];
  const float mean = S * (1.f / DDIM);
  const float var = SQ * (1.f / DDIM) - mean * mean;
  const float rstd = rsqrtf(var + 1e-5f);
  const float* sc = ss + (size_t)b * 2 * DDIM;
#pragma unroll
  for (int i = 0; i < 8; ++i) {
    const int d = tid * 8 + i;
    float hn = (v[i] - mean) * rstd * g[d] + bb[d];
    hn = hn * (1.f + sc[d]) + sc[DDIM + d];
    float si = hn / (1.f + __expf(-hn));
    v8[i] = (__bf16)si;
  }
  *(bf16x8*)(row + tid * 8) = v8;
}

// ---------------------------------------------------------------------------
// K3: out[m_base..] = x + a @ out_W + out_b (fp32 out). 128x128 tile, 4 waves.
// v4: global_load_lds staging with source-side swizzle (see v4 notes).
// ---------------------------------------------------------------------------
__launch_bounds__(256, 2)
__global__ void k3_proj(const __bf16* __restrict__ a, const __bf16* __restrict__ oWT,
                        const float* __restrict__ ob, const float* __restrict__ x,
                        float* __restrict__ out, int m_base) {
  __shared__ __bf16 As[128 * 64];  // 16 KB (swizzled)
  __shared__ __bf16 Bs[128 * 64];  // 16 KB (swizzled)
  const int tid = threadIdx.x;
  const int w = tid >> 6, lane = tid & 63, q = lane >> 4, ln = lane & 15;
  const int wm = w >> 1, wn = w & 1;
  const int m0 = m_base + blockIdx.x * 128, n0 = blockIdx.y * 128;
  const int swz = (ln & 7) << 3;
  // per-lane staging source offsets: row-in-chunk rr, pre-swizzled col co
  const int rr = lane >> 3;
  const int co = ((lane & 7) ^ rr) * 8;
  // acc[j][i]: D row = n-sub (wn*64 + j*16 + q*4 + r), col = m-sub (wm*64 + i*16 + ln)
  f32x4 acc[4][4] = {};

  for (int k0 = 0; k0 < 2048; k0 += 64) {
    __syncthreads();  // all readers done with As/Bs
#pragma unroll
    for (int p = 0; p < 4; ++p) {
      const int rbase = w * 32 + p * 8;           // wave-uniform
      gload_lds16(a   + (size_t)(m0 + rbase + rr) * DDIM + k0 + co, As + rbase * 64);
      gload_lds16(oWT + (size_t)(n0 + rbase + rr) * DDIM + k0 + co, Bs + rbase * 64);
    }
    __syncthreads();  // vmcnt(0) drained by barrier -> tiles ready
#pragma unroll
    for (int ks = 0; ks < 64; ks += 32) {
      bf16x8 af[4], bfr[4];
#pragma unroll
      for (int i = 0; i < 4; ++i)
        af[i] = *(const bf16x8*)(As + (wm * 64 + i * 16 + ln) * 64 + ((ks + q * 8) ^ swz));
#pragma unroll
      for (int j = 0; j < 4; ++j)
        bfr[j] = *(const bf16x8*)(Bs + (wn * 64 + j * 16 + ln) * 64 + ((ks + q * 8) ^ swz));
#pragma unroll
      for (int j = 0; j < 4; ++j)
#pragma unroll
        for (int i = 0; i < 4; ++i)
          acc[j][i] = __builtin_amdgcn_mfma_f32_16x16x32_bf16(bfr[j], af[i], acc[j][i], 0, 0, 0);
    }
  }

  // epilogue: + out_b + residual x, vectorized f32x4 (lane holds 4 consecutive n at one m)
#pragma unroll
  for (int j = 0; j < 4; ++j) {
    const int n = n0 + wn * 64 + j * 16 + q * 4;
    const f32x4 bn4 = *(const f32x4*)(ob + n);
#pragma unroll
    for (int i = 0; i < 4; ++i) {
      const int m = m0 + wm * 64 + i * 16 + ln;
      const f32x4 xr = *(const f32x4*)(x + (size_t)m * DDIM + n);
      f32x4 v;
#pragma unroll
      for (int r = 0; r < 4; ++r) v[r] = acc[j][i][r] + bn4[r] + xr[r];
      *(f32x4*)(out + (size_t)m * DDIM + n) = v;
    }
  }
}

// ---------------------------------------------------------------------------
// Buffer plan unchanged (see v1 comments).
// ---------------------------------------------------------------------------
extern "C" void kernel_launch(void* const* d_in, const int* in_sizes, int n_in,
                              void* d_out, int out_size, void* d_ws, size_t ws_size,
                              hipStream_t stream) {
  const float* x    = (const float*)d_in[0];
  const float* emb  = (const float*)d_in[1];
  const float* W1   = (const float*)d_in[2];
  const float* b1   = (const float*)d_in[3];
  const float* W2   = (const float*)d_in[4];
  const float* b2   = (const float*)d_in[5];
  const float* embW = (const float*)d_in[6];
  const float* embb = (const float*)d_in[7];
  const float* lng  = (const float*)d_in[8];
  const float* lnb  = (const float*)d_in[9];
  const float* outW = (const float*)d_in[10];
  const float* outb = (const float*)d_in[11];
  float* out = (float*)d_out;

  char* ob = (char*)d_out;
  __bf16* W1T  = (__bf16*)ob;                            // [0, 4MB)
  __bf16* W2T  = (__bf16*)(ob + (4 << 20));              // [4, 8MB)
  float*  pp   = (float*)(ob + (8 << 20));               // [8MB, +512KB)
  float*  ss   = (float*)(ob + (8 << 20) + (512 << 10)); // [8.5MB, +64KB)
  __bf16* oWT1 = (__bf16*)ob;                            // [0, 8MB) after k1
  __bf16* y    = (__bf16*)d_ws;                          // [0, 64MB)
  __bf16* oWT2 = (__bf16*)((char*)d_ws + (8 << 20));     // [8, 16MB), after k3a

  transpose_f32_bf16<<<dim3(32, 8, 8), 256, 0, stream>>>(W1, W1T, 256, 1024);
  transpose_f32_bf16<<<dim3(8, 32, 8), 256, 0, stream>>>(W2, W2T, 1024, 256);
  k0_partial<<<dim3(16, 8), 256, 0, stream>>>(emb, embW, pp);
  k0_reduce<<<16, 256, 0, stream>>>(pp, embb, ss);
  k1_expert_ffn<<<dim3(TOKENS / 64, 8), 512, 0, stream>>>(x, W1T, b1, W2T, b2, y);
  k2_ln_mod_silu<<<TOKENS, 256, 0, stream>>>(ss, lng, lnb, y);
  // W1T/W2T dead; overwrite with out_W^T (bf16)
  transpose_f32_bf16<<<dim3(64, 64, 1), 256, 0, stream>>>(outW, oWT1, 2048, 2048);
  // rows 2048..16383: reads oWT1 (d_out[0,8MB)), writes d_out[16MB,134MB)
  k3_proj<<<dim3(112, 16), 256, 0, stream>>>(y, oWT1, outb, x, out, 2048);
  // y-rows 2048..4095 (ws[8,16MB)) are dead now; stash a second out_W^T there
  transpose_f32_bf16<<<dim3(64, 64, 1), 256, 0, stream>>>(outW, oWT2, 2048, 2048);
  // rows 0..2047: reads oWT2 (ws), writes d_out[0,16MB)
  k3_proj<<<dim3(16, 16), 256, 0, stream>>>(y, oWT2, outb, x, out, 0);
}

// Round 5
// 761.982 us; speedup vs baseline: 1.0524x; 1.0524x over previous
//
#include <hip/hip_runtime.h>

typedef __attribute__((ext_vector_type(8))) __bf16 bf16x8;
typedef __attribute__((ext_vector_type(4))) __bf16 bf16x4;
typedef __attribute__((ext_vector_type(4))) float f32x4;

#define TOKENS 16384   // B*T
#define DDIM   2048
#define LAT    256
#define FFND   1024

// ---------------------------------------------------------------------------
// async global->LDS 16B copy (dest = wave-uniform base + lane*16B)
// ---------------------------------------------------------------------------
__device__ __forceinline__ void gload_lds16(const __bf16* g, __bf16* l) {
  __builtin_amdgcn_global_load_lds(
      (const __attribute__((address_space(1))) void*)g,
      (__attribute__((address_space(3))) void*)l, 16, 0, 0);
}

// ---------------------------------------------------------------------------
// Batched transpose + fp32->bf16 convert: src (batch, R, C) f32 -> dst (batch, C, R) bf16
// (still used for out_W)
// ---------------------------------------------------------------------------
__global__ void transpose_f32_bf16(const float* __restrict__ src, __bf16* __restrict__ dst,
                                   int R, int C) {
  __shared__ float tile[32][33];  // +1 pad breaks bank conflicts
  const int b = blockIdx.z;
  src += (size_t)b * R * C;
  dst += (size_t)b * R * C;
  const int c0 = blockIdx.x * 32, r0 = blockIdx.y * 32;
  const int tx = threadIdx.x & 31, ty = threadIdx.x >> 5;  // 256 threads: ty 0..7
  for (int i = ty; i < 32; i += 8)
    tile[i][tx] = src[(size_t)(r0 + i) * C + c0 + tx];
  __syncthreads();
  for (int i = ty; i < 32; i += 8)
    dst[(size_t)(c0 + i) * R + r0 + tx] = (__bf16)tile[tx][i];
}

// ---------------------------------------------------------------------------
// Weight repack into MFMA-fragment-contiguous layout.
// W is [e][Kdim][Fdim] f32 (contraction dim major). Output fragment layout:
//   P[((e*nF + F)*nK + K)*512 + lane*8 + t] = (bf16) W[e][K*32 + (lane>>4)*8 + t][F*16 + (lane&15)]
// so one wave b128 load at (base + lane*16B) delivers the 16x32 MFMA B-frag
// for rows F*16..+15, k K*32..+31 -- fully coalesced (v4's loads were
// 16-cache-line gathers at stride 512/2048B: the K1 latency source).
// ---------------------------------------------------------------------------
__global__ void pack_w(const float* __restrict__ W, __bf16* __restrict__ P,
                       int Kdim, int Fdim) {
  const int tid = threadIdx.x;
  const int lane = tid & 63;
  const int q = lane >> 4, ln = lane & 15;
  const int nF = Fdim >> 4;
  const int nK = Kdim >> 5;
  const int e = blockIdx.x / nF;
  const int F = blockIdx.x % nF;
  for (int kb = tid >> 6; kb < nK; kb += 8) {  // 512 threads: 8 kb slots/pass
    bf16x8 o;
#pragma unroll
    for (int t = 0; t < 8; ++t) {
      float v = W[((size_t)e * Kdim + kb * 32 + q * 8 + t) * Fdim + F * 16 + ln];
      o[t] = (__bf16)v;
    }
    *(bf16x8*)(P + ((size_t)blockIdx.x * nK + kb) * 512 + lane * 8) = o;
  }
}

// ---------------------------------------------------------------------------
// K0a: partial eo = silu(emb) @ emb_W over a 256-wide k-chunk.
// ---------------------------------------------------------------------------
__global__ void k0_partial(const float* __restrict__ emb, const float* __restrict__ embW,
                           float* __restrict__ pp) {
  __shared__ float se[4 * 256];
  const int tid = threadIdx.x;
  const int kc = blockIdx.y;
  const int kb = kc * 256;
  for (int i = tid; i < 1024; i += 256) {
    const int bb = i >> 8, kk = i & 255;
    float v = emb[bb * 2048 + kb + kk];
    se[i] = v / (1.f + __expf(-v));
  }
  __syncthreads();
  const int j = blockIdx.x * 256 + tid;
  float a0 = 0.f, a1 = 0.f, a2 = 0.f, a3 = 0.f;
  for (int k = 0; k < 256; ++k) {
    float wv = embW[(size_t)(kb + k) * 4096 + j];
    a0 += se[k] * wv;
    a1 += se[256 + k] * wv;
    a2 += se[512 + k] * wv;
    a3 += se[768 + k] * wv;
  }
  pp[(size_t)(kc * 4 + 0) * 4096 + j] = a0;
  pp[(size_t)(kc * 4 + 1) * 4096 + j] = a1;
  pp[(size_t)(kc * 4 + 2) * 4096 + j] = a2;
  pp[(size_t)(kc * 4 + 3) * 4096 + j] = a3;
}

// K0b: reduce partials + bias -> ss[b*4096 + j] (fp32)
__global__ void k0_reduce(const float* __restrict__ pp, const float* __restrict__ embb,
                          float* __restrict__ ss) {
  const int j = blockIdx.x * 256 + threadIdx.x;
  const float bb = embb[j];
#pragma unroll
  for (int b = 0; b < 4; ++b) {
    float s = bb;
#pragma unroll
    for (int kc = 0; kc < 8; ++kc) s += pp[(size_t)(kc * 4 + b) * 4096 + j];
    ss[b * 4096 + j] = s;
  }
}

// ---------------------------------------------------------------------------
// K=256 MFMA sweep on packed weights: acc[j][i] += Wfrag(j,k0b) x LDS-tile.
// wp: packed base for this wave's 2 F-blocks; frag addr = wp + j*jstride +
// k0b*512 + lane*8 (contiguous 1KB per wave instruction).
// ---------------------------------------------------------------------------
__device__ __forceinline__ void gemm_acc(const __bf16* __restrict__ wp, int jstride,
                                         const __bf16* lds, int swz, int lane,
                                         f32x4 (&acc)[2][4]) {
  const int ln = lane & 15, q = lane >> 4;
#pragma unroll
  for (int k0b = 0; k0b < 8; ++k0b) {
    bf16x8 af[4], bfr[2];
#pragma unroll
    for (int j = 0; j < 2; ++j)
      bfr[j] = *(const bf16x8*)(wp + j * jstride + k0b * 512 + lane * 8);
#pragma unroll
    for (int i = 0; i < 4; ++i)
      af[i] = *(const bf16x8*)(lds + (i * 16 + ln) * 256 + ((k0b * 32 + q * 8) ^ swz));
#pragma unroll
    for (int j = 0; j < 2; ++j)
#pragma unroll
      for (int i = 0; i < 4; ++i)
        acc[j][i] = __builtin_amdgcn_mfma_f32_16x16x32_bf16(bfr[j], af[i], acc[j][i], 0, 0, 0);
  }
}

// ---------------------------------------------------------------------------
// K1: fused expert FFN. Block = 64 tokens x 1 expert, 8 waves (512 thr).
//
// v6 = v4 structure (315us, 16 waves/CU; v5's (512,2)+prefetch regressed:
//     compiler re-sank the prefetch, VGPR=72) + fragment-packed weights:
//     v4's weight loads were 16-line gathers (16 lanes x stride 512B/2048B
//     per instruction) -- ~1.3e5 cyc/CU of TA serialization + amplified
//     vmcnt latency that 4 waves/SIMD can't hide (all pipes <30%). Packed
//     layout makes every weight fragment a contiguous 1KB wave load.
//     Same values, same MFMA order -> bit-exact vs v4.
// ---------------------------------------------------------------------------
__launch_bounds__(512, 4)
__global__ void k1_expert_ffn(const float* __restrict__ x, const __bf16* __restrict__ W1P,
                              const float* __restrict__ b1, const __bf16* __restrict__ W2P,
                              const float* __restrict__ b2, __bf16* __restrict__ y) {
  __shared__ __bf16 xs[64 * 256];     // 32 KB  x tile [m][l] (bf16, swizzled)
  __shared__ __bf16 hs[64 * 256];     // 32 KB  gelu(h) chunk [m][f_local] (swizzled)

  const int tid = threadIdx.x;
  const int w = tid >> 6;             // 0..7
  const int lane = tid & 63;
  const int q = lane >> 4;
  const int ln = lane & 15;
  const int m0 = blockIdx.x * 64;
  const int e = blockIdx.y;
  const int swz = (ln & 7) << 3;

  // stage x tile (64 x 256 fp32) -> bf16 LDS (swizzled); 8 rows/pass, 8 passes
  {
    const int r0 = tid >> 6;
    const int c = (tid & 63) * 4;
#pragma unroll
    for (int p = 0; p < 8; ++p) {
      const int r = r0 + p * 8;
      f32x4 v = *(const f32x4*)(x + (size_t)(m0 + r) * DDIM + e * LAT + c);
      bf16x4 o;
      o[0] = (__bf16)v[0]; o[1] = (__bf16)v[1]; o[2] = (__bf16)v[2]; o[3] = (__bf16)v[3];
      *(bf16x4*)(xs + r * 256 + (c ^ ((r & 7) << 3))) = o;
    }
  }

  // acc_y[j][i]: D row = latent l = w*32 + j*16 + q*4 + r, col = token = i*16 + ln
  f32x4 acc_y[2][4];
#pragma unroll
  for (int j = 0; j < 2; ++j) {
    f32x4 bv = *(const f32x4*)(b2 + e * LAT + w * 32 + j * 16 + q * 4);
#pragma unroll
    for (int i = 0; i < 4; ++i) acc_y[j][i] = bv;
  }

  f32x4 acc_h[2][4];

  // packed-weight bases:
  //  W1: F-block = e*64 + fc*16 + w*2 + j, K-blocks 8  -> jstride 8*512
  //  W2: F-block = e*16 + w*2 + j, K-block = fc*8+k0b (32) -> jstride 32*512
  const __bf16* wp1base = W1P + ((size_t)(e * 64 + w * 2) * 8) * 512;
  const __bf16* wp2base = W2P + ((size_t)(e * 16 + w * 2) * 32) * 512;

  __syncthreads();  // xs ready

  // GEMM1 chunk 0 -> acc_h
#pragma unroll
  for (int j = 0; j < 2; ++j) {
    f32x4 bv = *(const f32x4*)(b1 + e * FFND + w * 32 + j * 16 + q * 4);
#pragma unroll
    for (int i = 0; i < 4; ++i) acc_h[j][i] = bv;
  }
  gemm_acc(wp1base, 8 * 512, xs, swz, lane, acc_h);

  for (int fc = 0; fc < 4; ++fc) {
    // pack GELU(acc_h) -> hs (hs fully consumed before the barrier below)
#pragma unroll
    for (int j = 0; j < 2; ++j)
#pragma unroll
      for (int i = 0; i < 4; ++i) {
        const int tok = i * 16 + ln;
        const int fcol = w * 32 + j * 16 + q * 4;
        bf16x4 o;
#pragma unroll
        for (int r = 0; r < 4; ++r) {
          float vv = acc_h[j][i][r];
          // gelu(v) = v * sigmoid(1.5957691*v*(1+0.044715*v^2))  [tanh form]
          float u2 = -1.5957691216057308f * vv * (1.0f + 0.044715f * vv * vv);
          u2 = fminf(u2, 80.f);  // overflow guard
          float ge = vv * __builtin_amdgcn_rcpf(1.0f + __expf(u2));
          o[r] = (__bf16)ge;
        }
        *(bf16x4*)(hs + tok * 256 + (fcol ^ ((tok & 7) << 3))) = o;
      }

    __syncthreads();  // hs ready

    if (fc < 3) {
      // GEMM1(fc+1): xs-only, independent of GEMM2(fc) -> overlapped streams
#pragma unroll
      for (int j = 0; j < 2; ++j) {
        f32x4 bv = *(const f32x4*)(b1 + e * FFND + (fc + 1) * 256 + w * 32 + j * 16 + q * 4);
#pragma unroll
        for (int i = 0; i < 4; ++i) acc_h[j][i] = bv;
      }
      gemm_acc(wp1base + (size_t)(fc + 1) * 16 * 8 * 512, 8 * 512, xs, swz, lane, acc_h);
    }

    // GEMM2(fc): acc_y += W2-frags x hs
    gemm_acc(wp2base + (size_t)fc * 8 * 512, 32 * 512, hs, swz, lane, acc_y);

    __syncthreads();  // hs consumed by all waves before next pack overwrites it
  }

  // store y (bf16): lane holds 4 consecutive latent cols at one token -> b64 stores
#pragma unroll
  for (int j = 0; j < 2; ++j)
#pragma unroll
    for (int i = 0; i < 4; ++i) {
      const int tok = i * 16 + ln;
      const int l = w * 32 + j * 16 + q * 4;
      bf16x4 o;
#pragma unroll
      for (int r = 0; r < 4; ++r) o[r] = (__bf16)acc_y[j][i][r];
      *(bf16x4*)(y + (size_t)(m0 + tok) * DDIM + e * LAT + l) = o;
    }
}

// ---------------------------------------------------------------------------
// K2: per-token LN + (1+scale)/shift modulation + SiLU, in place on y (bf16).
// ---------------------------------------------------------------------------
__global__ void k2_ln_mod_silu(const float* __restrict__ ss, const float* __restrict__ g,
                               const float* __restrict__ bb, __bf16* __restrict__ y) {
  __shared__ float red[8];
  const int t = blockIdx.x;     // token
  const int b = t >> 12;        // batch = token / 4096
  const int tid = threadIdx.x;
  __bf16* row = y + (size_t)t * DDIM;
  bf16x8 v8 = *(bf16x8*)(row + tid * 8);
  float v[8], s = 0.f, sq = 0.f;
#pragma unroll
  for (int i = 0; i < 8; ++i) {
    v[i] = (float)v8[i];
    s += v[i];
    sq += v[i] * v[i];
  }
#pragma unroll
  for (int off = 32; off > 0; off >>= 1) {
    s += __shfl_down(s, off);
    sq += __shfl_down(sq, off);
  }
  if ((tid & 63) == 0) {
    red[tid >> 6] = s;
    red[4 + (tid >> 6)] = sq;
  }
  __syncthreads();
  const float S = red[0] + red[1] + red[2] + red[3];
  const float SQ = red[4] + red[5] + red[6] + red[7];
  const float mean = S * (1.f / DDIM);
  const float var = SQ * (1.f / DDIM) - mean * mean;
  const float rstd = rsqrtf(var + 1e-5f);
  const float* sc = ss + (size_t)b * 2 * DDIM;
#pragma unroll
  for (int i = 0; i < 8; ++i) {
    const int d = tid * 8 + i;
    float hn = (v[i] - mean) * rstd * g[d] + bb[d];
    hn = hn * (1.f + sc[d]) + sc[DDIM + d];
    float si = hn / (1.f + __expf(-hn));
    v8[i] = (__bf16)si;
  }
  *(bf16x8*)(row + tid * 8) = v8;
}

// ---------------------------------------------------------------------------
// K3: out[m_base..] = x + a @ out_W + out_b (fp32 out). 128x128 tile, 4 waves.
// v4: global_load_lds staging with source-side swizzle (see v4 notes).
// ---------------------------------------------------------------------------
__launch_bounds__(256, 2)
__global__ void k3_proj(const __bf16* __restrict__ a, const __bf16* __restrict__ oWT,
                        const float* __restrict__ ob, const float* __restrict__ x,
                        float* __restrict__ out, int m_base) {
  __shared__ __bf16 As[128 * 64];  // 16 KB (swizzled)
  __shared__ __bf16 Bs[128 * 64];  // 16 KB (swizzled)
  const int tid = threadIdx.x;
  const int w = tid >> 6, lane = tid & 63, q = lane >> 4, ln = lane & 15;
  const int wm = w >> 1, wn = w & 1;
  const int m0 = m_base + blockIdx.x * 128, n0 = blockIdx.y * 128;
  const int swz = (ln & 7) << 3;
  // per-lane staging source offsets: row-in-chunk rr, pre-swizzled col co
  const int rr = lane >> 3;
  const int co = ((lane & 7) ^ rr) * 8;
  // acc[j][i]: D row = n-sub (wn*64 + j*16 + q*4 + r), col = m-sub (wm*64 + i*16 + ln)
  f32x4 acc[4][4] = {};

  for (int k0 = 0; k0 < 2048; k0 += 64) {
    __syncthreads();  // all readers done with As/Bs
#pragma unroll
    for (int p = 0; p < 4; ++p) {
      const int rbase = w * 32 + p * 8;           // wave-uniform
      gload_lds16(a   + (size_t)(m0 + rbase + rr) * DDIM + k0 + co, As + rbase * 64);
      gload_lds16(oWT + (size_t)(n0 + rbase + rr) * DDIM + k0 + co, Bs + rbase * 64);
    }
    __syncthreads();  // vmcnt(0) drained by barrier -> tiles ready
#pragma unroll
    for (int ks = 0; ks < 64; ks += 32) {
      bf16x8 af[4], bfr[4];
#pragma unroll
      for (int i = 0; i < 4; ++i)
        af[i] = *(const bf16x8*)(As + (wm * 64 + i * 16 + ln) * 64 + ((ks + q * 8) ^ swz));
#pragma unroll
      for (int j = 0; j < 4; ++j)
        bfr[j] = *(const bf16x8*)(Bs + (wn * 64 + j * 16 + ln) * 64 + ((ks + q * 8) ^ swz));
#pragma unroll
      for (int j = 0; j < 4; ++j)
#pragma unroll
        for (int i = 0; i < 4; ++i)
          acc[j][i] = __builtin_amdgcn_mfma_f32_16x16x32_bf16(bfr[j], af[i], acc[j][i], 0, 0, 0);
    }
  }

  // epilogue: + out_b + residual x, vectorized f32x4 (lane holds 4 consecutive n at one m)
#pragma unroll
  for (int j = 0; j < 4; ++j) {
    const int n = n0 + wn * 64 + j * 16 + q * 4;
    const f32x4 bn4 = *(const f32x4*)(ob + n);
#pragma unroll
    for (int i = 0; i < 4; ++i) {
      const int m = m0 + wm * 64 + i * 16 + ln;
      const f32x4 xr = *(const f32x4*)(x + (size_t)m * DDIM + n);
      f32x4 v;
#pragma unroll
      for (int r = 0; r < 4; ++r) v[r] = acc[j][i][r] + bn4[r] + xr[r];
      *(f32x4*)(out + (size_t)m * DDIM + n) = v;
    }
  }
}

// ---------------------------------------------------------------------------
// Buffer plan (same regions as before; W1P/W2P replace W1T/W2T):
//   d_out scratch: W1P [0,4MB) bf16, W2P [4,8MB) bf16, pp [8MB,+512KB),
//   ss [8.5MB,+64KB); after k1: oWT1 over [0,8MB).
//   d_ws: y [0,64MB); oWT2 at [8,16MB) after k3a.
// ---------------------------------------------------------------------------
extern "C" void kernel_launch(void* const* d_in, const int* in_sizes, int n_in,
                              void* d_out, int out_size, void* d_ws, size_t ws_size,
                              hipStream_t stream) {
  const float* x    = (const float*)d_in[0];
  const float* emb  = (const float*)d_in[1];
  const float* W1   = (const float*)d_in[2];
  const float* b1   = (const float*)d_in[3];
  const float* W2   = (const float*)d_in[4];
  const float* b2   = (const float*)d_in[5];
  const float* embW = (const float*)d_in[6];
  const float* embb = (const float*)d_in[7];
  const float* lng  = (const float*)d_in[8];
  const float* lnb  = (const float*)d_in[9];
  const float* outW = (const float*)d_in[10];
  const float* outb = (const float*)d_in[11];
  float* out = (float*)d_out;

  char* ob = (char*)d_out;
  __bf16* W1P  = (__bf16*)ob;                            // [0, 4MB)
  __bf16* W2P  = (__bf16*)(ob + (4 << 20));              // [4, 8MB)
  float*  pp   = (float*)(ob + (8 << 20));               // [8MB, +512KB)
  float*  ss   = (float*)(ob + (8 << 20) + (512 << 10)); // [8.5MB, +64KB)
  __bf16* oWT1 = (__bf16*)ob;                            // [0, 8MB) after k1
  __bf16* y    = (__bf16*)d_ws;                          // [0, 64MB)
  __bf16* oWT2 = (__bf16*)((char*)d_ws + (8 << 20));     // [8, 16MB), after k3a

  // pack W1 (8,256,1024) and W2 (8,1024,256) into fragment layout
  pack_w<<<512, 512, 0, stream>>>(W1, W1P, 256, 1024);
  pack_w<<<128, 512, 0, stream>>>(W2, W2P, 1024, 256);
  k0_partial<<<dim3(16, 8), 256, 0, stream>>>(emb, embW, pp);
  k0_reduce<<<16, 256, 0, stream>>>(pp, embb, ss);
  k1_expert_ffn<<<dim3(TOKENS / 64, 8), 512, 0, stream>>>(x, W1P, b1, W2P, b2, y);
  k2_ln_mod_silu<<<TOKENS, 256, 0, stream>>>(ss, lng, lnb, y);
  // W1P/W2P dead; overwrite with out_W^T (bf16)
  transpose_f32_bf16<<<dim3(64, 64, 1), 256, 0, stream>>>(outW, oWT1, 2048, 2048);
  // rows 2048..16383: reads oWT1 (d_out[0,8MB)), writes d_out[16MB,134MB)
  k3_proj<<<dim3(112, 16), 256, 0, stream>>>(y, oWT1, outb, x, out, 2048);
  // y-rows 2048..4095 (ws[8,16MB)) are dead now; stash a second out_W^T there
  transpose_f32_bf16<<<dim3(64, 64, 1), 256, 0, stream>>>(outW, oWT2, 2048, 2048);
  // rows 0..2047: reads oWT2 (ws), writes d_out[0,16MB)
  k3_proj<<<dim3(16, 16), 256, 0, stream>>>(y, oWT2, outb, x, out, 0);
}